// Round 6
// baseline (9689.533 us; speedup 1.0000x reference)
//
#include <hip/hip_runtime.h>
#include <hip/hip_bf16.h>

#define NSTEP 50
#define BSZ   1024
#define HD    256
#define RPB   4
#define NEG_INF (-__builtin_inff())

#define OFF_SEL ((size_t)BSZ * NSTEP * NSTEP)          // 2,560,000
#define OFF_ETA (OFF_SEL + (size_t)BSZ * NSTEP)        // 2,611,200

__device__ __forceinline__ float sigf(float x)      { return 1.f / (1.f + __expf(-x)); }
__device__ __forceinline__ float tanh_fast(float x) { return 1.f - 2.f / (__expf(2.f * x) + 1.f); }

__device__ __forceinline__ float wave_sum(float v) {
#pragma unroll
  for (int o = 1; o < 64; o <<= 1) v += __shfl_xor(v, o);
  return v;
}
__device__ __forceinline__ float wave_max(float v) {
#pragma unroll
  for (int o = 1; o < 64; o <<= 1) v = fmaxf(v, __shfl_xor(v, o));
  return v;
}

// wT2[k][4*col+g] = W[g*256+col][k]; bc[j]=b_ih[j]+b_hh[j]; wqT*[k][col] = wq[col][k]
__global__ __launch_bounds__(256) void init_kernel(
    const float* __restrict__ w_ih, const float* __restrict__ w_hh,
    const float* __restrict__ b_ih, const float* __restrict__ b_hh,
    const float* __restrict__ glp_wq, const float* __restrict__ ptr_wq,
    float* __restrict__ wT2, float* __restrict__ bc,
    float* __restrict__ wqTg, float* __restrict__ wqTp)
{
  const int bid = blockIdx.x, tid = threadIdx.x;
  if (bid < 512) {
    const int k = bid;
    const float* src = (k < 256) ? (w_ih + k) : (w_hh + (k - 256));
#pragma unroll
    for (int g = 0; g < 4; ++g)
      wT2[(size_t)k * 1024 + tid * 4 + g] = src[(size_t)(g * 256 + tid) * 256];
  } else if (bid < 516) {
    const int j = (bid - 512) * 256 + tid;
    bc[j] = b_ih[j] + b_hh[j];
  } else {
    const int k = bid - 516;
    wqTg[(size_t)k * 256 + tid] = glp_wq[(size_t)tid * 256 + k];
    wqTp[(size_t)k * 256 + tid] = ptr_wq[(size_t)tid * 256 + k];
  }
}

// et[b][h][n] = 2*( sum_k context[n][b][k]*wr[h][k] + br[h] ), n-padded stride 50
// one block per b; thread = h; c_lds staged tile; k4-outer, 50-acc registers.
__global__ __launch_bounds__(256) void et_kernel(
    const float* __restrict__ context,
    const float* __restrict__ wr, const float* __restrict__ br,
    float* __restrict__ et)
{
  __shared__ float c_lds[50][260];
  const int b = blockIdx.x, tid = threadIdx.x;
  for (int i = tid; i < 50 * 256; i += 256) {
    const int n = i >> 8, k = i & 255;
    c_lds[n][k] = context[((size_t)n * BSZ + b) * HD + k];
  }
  __syncthreads();
  float acc[50];
#pragma unroll
  for (int n = 0; n < 50; ++n) acc[n] = 0.f;
  const float* wrh = wr + (size_t)tid * HD;
  for (int k4 = 0; k4 < 64; ++k4) {
    const float4 w4 = *(const float4*)&wrh[k4 * 4];
#pragma unroll
    for (int n = 0; n < 50; ++n) {
      const float4 c4 = *(const float4*)&c_lds[n][k4 * 4];
      acc[n] += c4.x * w4.x + c4.y * w4.y + c4.z * w4.z + c4.w * w4.w;
    }
  }
  const float bb = br[tid];
  float* dst = et + ((size_t)b * HD + tid) * NSTEP;
#pragma unroll
  for (int n = 0; n < 50; ++n) dst[n] = 2.f * (acc[n] + bb);
}

// persistent decoder: 256 blocks x 512 threads (8 waves), 4 rows/block, 1 block/CU
__global__ __launch_bounds__(512) void dec_kernel(
    const float* __restrict__ start_fea,
    const float* __restrict__ decoder_input,
    const float* __restrict__ embedded,
    const float* __restrict__ hidden_h,
    const float* __restrict__ hidden_c,
    const float* __restrict__ context,
    const unsigned char* __restrict__ vmask,
    const float* __restrict__ glp_bq, const float* __restrict__ glp_v,
    const float* __restrict__ ptr_bq, const float* __restrict__ ptr_v,
    const float* __restrict__ fn_w,
    const float* __restrict__ eta_lw, const float* __restrict__ eta_lb,
    const float* __restrict__ wT2, const float* __restrict__ bc,
    const float* __restrict__ wqTg, const float* __restrict__ wqTp,
    const float* __restrict__ et_glp, const float* __restrict__ et_ptr,
    float* __restrict__ out)
{
  __shared__ float a_lds[RPB][512];          // [r][0..255]=x, [r][256..511]=h
  __shared__ float z_lds[RPB][1024];         // A: z(4col+g) | B/E partials | G
  __shared__ float qf_lds[RPB][256];         // 2*(q+bias)
  __shared__ float up_lds[RPB][2][64];       // u partials per half-wave
  __shared__ float p_lds[RPB][64];           // P/2 per lane=n (0 beyond 49)
  __shared__ float vv_lds[2][256];           // v_glp, v_ptr
  __shared__ unsigned char mask_lds[RPB][64];
  __shared__ int   idx_lds[RPB];
  __shared__ float red_lds[8][2];
  __shared__ float eta_lds[RPB];

  const int tid  = threadIdx.x;
  const int col  = tid & 255;
  const int hf   = tid >> 8;
  const int wav  = tid >> 6;                 // 0..7
  const int lane = tid & 63;
  const int b0   = blockIdx.x * RPB;
  const int k0   = hf << 7;
  const int j2   = tid * 2;
  const int cr   = wav >> 1;                 // C/F row (2 waves per row)
  const int ch   = wav & 1;                  // h-half

  float c_reg[2], ln_reg[2];

  // ---- init state ----
#pragma unroll
  for (int rr = 0; rr < 2; ++rr) {
    const int r = hf * 2 + rr, b = b0 + r;
    a_lds[r][col]       = decoder_input[(size_t)b * HD + col];
    a_lds[r][256 + col] = hidden_h[(size_t)b * HD + col];
    c_reg[rr] = hidden_c[(size_t)b * HD + col];
    float fn = 0.f;
#pragma unroll
    for (int k = 0; k < 5; ++k) fn += start_fea[b * 5 + k] * fn_w[col * 5 + k];
    ln_reg[rr] = fn;
  }
  if (hf == 0) vv_lds[0][col] = glp_v[col]; else vv_lds[1][col] = ptr_v[col];
  if (tid < RPB * NSTEP) {
    const int r = tid / NSTEP, n = tid - r * NSTEP;
    mask_lds[r][n] = vmask[(size_t)(b0 + r) * NSTEP + n];
  }
  if (tid < RPB) { eta_lds[tid] = 0.f; idx_lds[tid] = 0; }
  __syncthreads();
  if (tid < RPB) {
    bool all = true;
    for (int n = 0; n < NSTEP; ++n) all = all && (mask_lds[tid][n] != 0);
    if (all) mask_lds[tid][NSTEP - 1] = 0;
  }
  __syncthreads();

  const float bch0 = bc[col], bch1 = bc[col + 256], bch2 = bc[col + 512], bch3 = bc[col + 768];
  const float lw0 = eta_lw[col], lw1 = eta_lw[HD + col];
  const float etaB = eta_lb[0];
  const float bqg = glp_bq[col], bqp = ptr_bq[col];

  for (int t = 0; t < NSTEP; ++t) {
    // ---- A: z[j2,j2+1] for 4 rows, K=512 ([x|h]); W read once per block ----
    {
      float2 acc[RPB];
#pragma unroll
      for (int i = 0; i < RPB; ++i) acc[i] = make_float2(0.f, 0.f);
      for (int k = 0; k < 512; k += 4) {
        float4 a4[RPB];
#pragma unroll
        for (int i = 0; i < RPB; ++i) a4[i] = *(const float4*)&a_lds[i][k];
        const float2 w0 = *(const float2*)&wT2[(size_t)(k + 0) * 1024 + j2];
        const float2 w1 = *(const float2*)&wT2[(size_t)(k + 1) * 1024 + j2];
        const float2 w2 = *(const float2*)&wT2[(size_t)(k + 2) * 1024 + j2];
        const float2 w3 = *(const float2*)&wT2[(size_t)(k + 3) * 1024 + j2];
#pragma unroll
        for (int i = 0; i < RPB; ++i) {
          acc[i].x += a4[i].x * w0.x + a4[i].y * w1.x + a4[i].z * w2.x + a4[i].w * w3.x;
          acc[i].y += a4[i].x * w0.y + a4[i].y * w1.y + a4[i].z * w2.y + a4[i].w * w3.y;
        }
      }
#pragma unroll
      for (int i = 0; i < RPB; ++i) *(float2*)&z_lds[i][j2] = acc[i];
    }
    __syncthreads();
    // ---- gates ----
#pragma unroll
    for (int rr = 0; rr < 2; ++rr) {
      const int r = hf * 2 + rr;
      const float4 z4 = *(const float4*)&z_lds[r][col << 2];
      const float zi = z4.x + bch0, zf = z4.y + bch1, zg = z4.z + bch2, zo = z4.w + bch3;
      const float cn = sigf(zf) * c_reg[rr] + sigf(zi) * tanh_fast(zg);
      c_reg[rr] = cn;
      a_lds[r][256 + col] = sigf(zo) * tanh_fast(cn);
    }
    __syncthreads();
    // ---- B: q_glp partials (k-split over hf) ----
    {
      float accB[RPB] = {0.f, 0.f, 0.f, 0.f};
      for (int k = k0; k < k0 + 128; k += 4) {
        float4 a4[RPB];
#pragma unroll
        for (int i = 0; i < RPB; ++i) a4[i] = *(const float4*)&a_lds[i][256 + k];
        const float w0 = wqTg[(size_t)(k + 0) * 256 + col];
        const float w1 = wqTg[(size_t)(k + 1) * 256 + col];
        const float w2 = wqTg[(size_t)(k + 2) * 256 + col];
        const float w3 = wqTg[(size_t)(k + 3) * 256 + col];
#pragma unroll
        for (int i = 0; i < RPB; ++i)
          accB[i] += a4[i].x * w0 + a4[i].y * w1 + a4[i].z * w2 + a4[i].w * w3;
      }
#pragma unroll
      for (int i = 0; i < RPB; ++i) z_lds[i][(hf << 8) + col] = accB[i];
    }
    __syncthreads();
    // ---- B2: qf = 2*(q+bias) ----
#pragma unroll
    for (int rr = 0; rr < 2; ++rr) {
      const int r = hf * 2 + rr;
      qf_lds[r][col] = 2.f * (z_lds[r][col] + z_lds[r][256 + col] + bqg);
    }
    __syncthreads();
    // ---- C1: u_glp streaming (lane=n, loop h; e_t pre-doubled) ----
    {
      const int r = cr, b = b0 + r;
      const float* et = et_glp + ((size_t)b * HD + (ch << 7)) * NSTEP + lane;
      const float* qf = &qf_lds[r][ch << 7];
      const float* vv = &vv_lds[0][ch << 7];
      float u = 0.f;
#pragma unroll 4
      for (int h = 0; h < 128; ++h) {
        const float x2 = qf[h] + et[h * NSTEP];
        const float th = 1.f - 2.f / (__expf(x2) + 1.f);
        u = fmaf(vv[h], th, u);
      }
      up_lds[r][ch][lane] = u;
    }
    __syncthreads();
    // ---- C2: masked softmax per row (wave=r), P/2 to p_lds ----
    if (wav < RPB) {
      const int r = wav;
      const bool mk = (lane < NSTEP) ? (mask_lds[r][lane] != 0) : true;
      const float u = up_lds[r][0][lane] + up_lds[r][1][lane];
      const float uv = mk ? NEG_INF : u;
      const float m  = wave_max(uv);
      const float ex = mk ? 0.f : __expf(uv - m);
      const float ss = wave_sum(ex);
      p_lds[r][lane] = 0.5f * (ex / ss);
    }
    __syncthreads();
    // ---- G: g_l[h] per col-thread, float2 over n (L2-resident tile re-read) ----
#pragma unroll
    for (int rr = 0; rr < 2; ++rr) {
      const int r = hf * 2 + rr, b = b0 + r;
      const float2* eb = (const float2*)(et_glp + ((size_t)b * HD + col) * NSTEP);
      float acc = 0.f;
#pragma unroll
      for (int q = 0; q < 25; ++q) {
        const float2 e2 = eb[q];
        const float2 p2 = *(const float2*)&p_lds[r][q * 2];
        acc += e2.x * p2.x + e2.y * p2.y;
      }
      z_lds[r][col] = acc;   // = sum_n P[n]*e[n][col]
    }
    __syncthreads();
    // ---- E: q_ptr partials from G (k-split over hf) ----
    {
      float accE[RPB] = {0.f, 0.f, 0.f, 0.f};
      for (int k = k0; k < k0 + 128; k += 4) {
        float4 g4[RPB];
#pragma unroll
        for (int i = 0; i < RPB; ++i) g4[i] = *(const float4*)&z_lds[i][k];
        const float w0 = wqTp[(size_t)(k + 0) * 256 + col];
        const float w1 = wqTp[(size_t)(k + 1) * 256 + col];
        const float w2 = wqTp[(size_t)(k + 2) * 256 + col];
        const float w3 = wqTp[(size_t)(k + 3) * 256 + col];
#pragma unroll
        for (int i = 0; i < RPB; ++i)
          accE[i] += g4[i].x * w0 + g4[i].y * w1 + g4[i].z * w2 + g4[i].w * w3;
      }
#pragma unroll
      for (int i = 0; i < RPB; ++i) z_lds[i][512 + (hf << 8) + col] = accE[i];
    }
    __syncthreads();
    // ---- E2: qf = 2*(q_ptr+bias) ----
#pragma unroll
    for (int rr = 0; rr < 2; ++rr) {
      const int r = hf * 2 + rr;
      qf_lds[r][col] = 2.f * (z_lds[r][512 + col] + z_lds[r][768 + col] + bqp);
    }
    __syncthreads();
    // ---- F: u_ptr streaming ----
    {
      const int r = cr, b = b0 + r;
      const float* et = et_ptr + ((size_t)b * HD + (ch << 7)) * NSTEP + lane;
      const float* qf = &qf_lds[r][ch << 7];
      const float* vv = &vv_lds[1][ch << 7];
      float u = 0.f;
#pragma unroll 4
      for (int h = 0; h < 128; ++h) {
        const float x2 = qf[h] + et[h * NSTEP];
        const float th = 1.f - 2.f / (__expf(x2) + 1.f);
        u = fmaf(vv[h], th, u);
      }
      up_lds[r][ch][lane] = u;
    }
    __syncthreads();
    // ---- F2: logits, log_softmax (finite clamp), argmax ----
    if (wav < RPB) {
      const int r = wav, b = b0 + r;
      const bool mk = (lane < NSTEP) ? (mask_lds[r][lane] != 0) : true;
      const float u = up_lds[r][0][lane] + up_lds[r][1][lane];
      const float lg = mk ? NEG_INF : (10.f * tanh_fast(u));
      const float m  = wave_max(lg);
      const float ex = mk ? 0.f : __expf(lg - m);
      const float ss = wave_sum(ex);
      const float ls = __logf(ss);
      if (lane < NSTEP)
        out[(size_t)b * (NSTEP * NSTEP) + (size_t)t * NSTEP + lane] =
            mk ? -1.0e30f : ((lg - m) - ls);
      float av = lg;
      int   ai = lane;
#pragma unroll
      for (int o = 1; o < 64; o <<= 1) {
        const float ov = __shfl_xor(av, o);
        const int   oi = __shfl_xor(ai, o);
        if (ov > av || (ov == av && oi < ai)) { av = ov; ai = oi; }
      }
      if (lane == 0) {
        idx_lds[r] = ai;
        out[OFF_SEL + (size_t)b * NSTEP + t] = (float)ai;
      }
    }
    __syncthreads();
    // ---- G2: gathers + eta + next x ----
    {
      float pr[2];
#pragma unroll
      for (int rr = 0; rr < 2; ++rr) {
        const int r = hf * 2 + rr, b = b0 + r;
        const int ix = idx_lds[r];
        const float cur = context[((size_t)ix * BSZ + b) * HD + col];
        pr[rr] = ln_reg[rr] * lw0 + cur * lw1;
        ln_reg[rr] = cur;
        a_lds[r][col] = embedded[((size_t)ix * BSZ + b) * HD + col];
      }
#pragma unroll
      for (int o = 1; o < 64; o <<= 1) {
        pr[0] += __shfl_xor(pr[0], o);
        pr[1] += __shfl_xor(pr[1], o);
      }
      if (lane == 0) { red_lds[wav][0] = pr[0]; red_lds[wav][1] = pr[1]; }
    }
    __syncthreads();
    if (tid < RPB) {
      const int r = tid;
      const int w0 = (r >> 1) * 4, rr = r & 1;
      const float s = red_lds[w0][rr] + red_lds[w0 + 1][rr]
                    + red_lds[w0 + 2][rr] + red_lds[w0 + 3][rr];
      const float ev = eta_lds[r] + s + etaB;
      eta_lds[r] = ev;
      out[OFF_ETA + (size_t)(b0 + r) * NSTEP + t] = ev;
      const int ix = idx_lds[r];
      mask_lds[r][ix] = 1;
      bool all = true;
      for (int n = 0; n < NSTEP; ++n) all = all && (mask_lds[r][n] != 0);
      if (all) mask_lds[r][NSTEP - 1] = 0;
    }
    __syncthreads();
  }
}

extern "C" void kernel_launch(void* const* d_in, const int* in_sizes, int n_in,
                              void* d_out, int out_size, void* d_ws, size_t ws_size,
                              hipStream_t stream) {
  const float* start_fea  = (const float*)d_in[0];
  const float* decoder_in = (const float*)d_in[1];
  const float* embedded   = (const float*)d_in[2];
  const float* hidden_h   = (const float*)d_in[3];
  const float* hidden_c   = (const float*)d_in[4];
  const float* context    = (const float*)d_in[5];
  // d_in[6] = V: unused by outputs
  const unsigned char* vmask = (const unsigned char*)d_in[7];
  const float* lstm_w_ih  = (const float*)d_in[8];
  const float* lstm_w_hh  = (const float*)d_in[9];
  const float* lstm_b_ih  = (const float*)d_in[10];
  const float* lstm_b_hh  = (const float*)d_in[11];
  const float* ptr_wq     = (const float*)d_in[12];
  const float* ptr_bq     = (const float*)d_in[13];
  const float* ptr_wr     = (const float*)d_in[14];
  const float* ptr_br     = (const float*)d_in[15];
  const float* ptr_v      = (const float*)d_in[16];
  const float* glp_wq     = (const float*)d_in[17];
  const float* glp_bq     = (const float*)d_in[18];
  const float* glp_wr     = (const float*)d_in[19];
  const float* glp_br     = (const float*)d_in[20];
  const float* glp_v      = (const float*)d_in[21];
  const float* fn_w       = (const float*)d_in[22];
  // d_in[23..26] = eta LSTM: dead code (outputs never read heh/cec)
  const float* eta_lw     = (const float*)d_in[27];
  const float* eta_lb     = (const float*)d_in[28];

  float* ws     = (float*)d_ws;
  float* wT2    = ws;                                      // 524,288 f32
  float* bc     = wT2 + (size_t)512 * 1024;                // 1,024
  float* wqTg   = bc + 1024;                               // 65,536
  float* wqTp   = wqTg + 65536;                            // 65,536
  float* et_glp = wqTp + 65536;                            // 13,107,200 (+64 pad)
  float* et_ptr = et_glp + (size_t)BSZ * HD * NSTEP + 64;  // 13,107,200 (+64 pad)

  init_kernel<<<772, 256, 0, stream>>>(lstm_w_ih, lstm_w_hh, lstm_b_ih, lstm_b_hh,
                                       glp_wq, ptr_wq, wT2, bc, wqTg, wqTp);
  et_kernel<<<BSZ, 256, 0, stream>>>(context, glp_wr, glp_br, et_glp);
  et_kernel<<<BSZ, 256, 0, stream>>>(context, ptr_wr, ptr_br, et_ptr);
  dec_kernel<<<BSZ / RPB, 512, 0, stream>>>(
      start_fea, decoder_in, embedded, hidden_h, hidden_c, context, vmask,
      glp_bq, glp_v, ptr_bq, ptr_v, fn_w, eta_lw, eta_lb,
      wT2, bc, wqTg, wqTp, et_glp, et_ptr, (float*)d_out);
}

// Round 7
// 5095.429 us; speedup vs baseline: 1.9016x; 1.9016x over previous
//
#include <hip/hip_runtime.h>
#include <hip/hip_bf16.h>

#define NSTEP 50
#define BSZ   1024
#define HD    256
#define RPB   4
#define NEG_INF (-__builtin_inff())

#define OFF_SEL ((size_t)BSZ * NSTEP * NSTEP)          // 2,560,000
#define OFF_ETA (OFF_SEL + (size_t)BSZ * NSTEP)        // 2,611,200

__device__ __forceinline__ float sigf(float x)      { return 1.f / (1.f + __expf(-x)); }
__device__ __forceinline__ float tanh_fast(float x) { return 1.f - 2.f / (__expf(2.f * x) + 1.f); }

__device__ __forceinline__ float wave_sum(float v) {
#pragma unroll
  for (int o = 1; o < 64; o <<= 1) v += __shfl_xor(v, o);
  return v;
}
__device__ __forceinline__ float wave_max(float v) {
#pragma unroll
  for (int o = 1; o < 64; o <<= 1) v = fmaxf(v, __shfl_xor(v, o));
  return v;
}

// wT2[k][4*col+g] = W[g*256+col][k]; bc[j]=b_ih[j]+b_hh[j]; wqT*[k][col] = wq[col][k]
__global__ __launch_bounds__(256) void init_kernel(
    const float* __restrict__ w_ih, const float* __restrict__ w_hh,
    const float* __restrict__ b_ih, const float* __restrict__ b_hh,
    const float* __restrict__ glp_wq, const float* __restrict__ ptr_wq,
    float* __restrict__ wT2, float* __restrict__ bc,
    float* __restrict__ wqTg, float* __restrict__ wqTp)
{
  const int bid = blockIdx.x, tid = threadIdx.x;
  if (bid < 512) {
    const int k = bid;
    const float* src = (k < 256) ? (w_ih + k) : (w_hh + (k - 256));
#pragma unroll
    for (int g = 0; g < 4; ++g)
      wT2[(size_t)k * 1024 + tid * 4 + g] = src[(size_t)(g * 256 + tid) * 256];
  } else if (bid < 516) {
    const int j = (bid - 512) * 256 + tid;
    bc[j] = b_ih[j] + b_hh[j];
  } else {
    const int k = bid - 516;
    wqTg[(size_t)k * 256 + tid] = glp_wq[(size_t)tid * 256 + k];
    wqTp[(size_t)k * 256 + tid] = ptr_wq[(size_t)tid * 256 + k];
  }
}

// e[b][n][g] = sum_h context[n][b][h]*wr[g][h] + br[g]   (R4 layout, float4-coalesced)
__global__ __launch_bounds__(256) void e_kernel(
    const float* __restrict__ context,
    const float* __restrict__ glp_wr, const float* __restrict__ glp_br,
    const float* __restrict__ ptr_wr, const float* __restrict__ ptr_br,
    float* __restrict__ e_glp, float* __restrict__ e_ptr)
{
  __shared__ float ctx_lds[32][256];
  const int tid = threadIdx.x;
  const int n   = blockIdx.x >> 5;
  const int b0  = (blockIdx.x & 31) << 5;
  const float* src = context + ((size_t)n * BSZ + b0) * HD;
  for (int i = tid; i < 32 * 64; i += 256) {
    const int row = i >> 6, k4 = (i & 63) << 2;
    *(float4*)&ctx_lds[row][k4] = *(const float4*)&src[row * HD + k4];
  }
  __syncthreads();
  const int g  = tid;
  const float bg = glp_br[g], bp = ptr_br[g];
  for (int rg = 0; rg < 2; ++rg) {
    float ag[16], ap[16];
#pragma unroll
    for (int i = 0; i < 16; ++i) { ag[i] = 0.f; ap[i] = 0.f; }
    for (int k = 0; k < 256; k += 4) {
      float4 wg = *(const float4*)&glp_wr[g * HD + k];
      float4 wp = *(const float4*)&ptr_wr[g * HD + k];
#pragma unroll
      for (int i = 0; i < 16; ++i) {
        float4 a = *(const float4*)&ctx_lds[rg * 16 + i][k];
        ag[i] += a.x * wg.x + a.y * wg.y + a.z * wg.z + a.w * wg.w;
        ap[i] += a.x * wp.x + a.y * wp.y + a.z * wp.z + a.w * wp.w;
      }
    }
#pragma unroll
    for (int i = 0; i < 16; ++i) {
      const int b = b0 + rg * 16 + i;
      e_glp[((size_t)b * NSTEP + n) * HD + g] = ag[i] + bg;
      e_ptr[((size_t)b * NSTEP + n) * HD + g] = ap[i] + bp;
    }
  }
}

// zx[n][b][4*col+g] = x_n[b] @ w_ih^T  (slot n==NSTEP -> decoder_input)
__global__ __launch_bounds__(256) void zx_kernel(
    const float* __restrict__ embedded, const float* __restrict__ decoder_input,
    const float* __restrict__ wT2, float* __restrict__ zx)
{
  __shared__ float x_lds[32][256];
  const int tid = threadIdx.x;
  const int n   = blockIdx.x >> 5;
  const int b0  = (blockIdx.x & 31) << 5;
  const float* src = (n < NSTEP) ? (embedded + ((size_t)n * BSZ + b0) * HD)
                                 : (decoder_input + (size_t)b0 * HD);
  for (int i = tid; i < 32 * 64; i += 256) {
    const int row = i >> 6, k4 = (i & 63) << 2;
    *(float4*)&x_lds[row][k4] = *(const float4*)&src[row * HD + k4];
  }
  __syncthreads();
  const float* wp = wT2 + (tid << 2);
  for (int rg = 0; rg < 2; ++rg) {
    float4 acc[16];
#pragma unroll
    for (int i = 0; i < 16; ++i) acc[i] = make_float4(0.f, 0.f, 0.f, 0.f);
    for (int k = 0; k < 256; k += 4) {
      float4 w0 = *(const float4*)(wp + (size_t)(k + 0) * 1024);
      float4 w1 = *(const float4*)(wp + (size_t)(k + 1) * 1024);
      float4 w2 = *(const float4*)(wp + (size_t)(k + 2) * 1024);
      float4 w3 = *(const float4*)(wp + (size_t)(k + 3) * 1024);
#pragma unroll
      for (int i = 0; i < 16; ++i) {
        float4 a = *(const float4*)&x_lds[rg * 16 + i][k];
        acc[i].x += a.x * w0.x + a.y * w1.x + a.z * w2.x + a.w * w3.x;
        acc[i].y += a.x * w0.y + a.y * w1.y + a.z * w2.y + a.w * w3.y;
        acc[i].z += a.x * w0.z + a.y * w1.z + a.z * w2.z + a.w * w3.z;
        acc[i].w += a.x * w0.w + a.y * w1.w + a.z * w2.w + a.w * w3.w;
      }
    }
#pragma unroll
    for (int i = 0; i < 16; ++i)
      *(float4*)&zx[((size_t)n * BSZ + (b0 + rg * 16 + i)) * 1024 + (tid << 2)] = acc[i];
  }
}

// persistent decoder: 256 blocks x 1024 threads (16 waves/CU), 4 rows/block
template <int PRE>
__global__ __launch_bounds__(1024) void dec_kernel(
    const float* __restrict__ start_fea,
    const float* __restrict__ decoder_input,
    const float* __restrict__ embedded,
    const float* __restrict__ hidden_h,
    const float* __restrict__ hidden_c,
    const float* __restrict__ context,
    const unsigned char* __restrict__ vmask,
    const float* __restrict__ glp_bq, const float* __restrict__ glp_v,
    const float* __restrict__ ptr_bq, const float* __restrict__ ptr_v,
    const float* __restrict__ fn_w,
    const float* __restrict__ eta_lw, const float* __restrict__ eta_lb,
    const float* __restrict__ wT2, const float* __restrict__ bc,
    const float* __restrict__ wqTg, const float* __restrict__ wqTp,
    const float* __restrict__ e_glp, const float* __restrict__ e_ptr,
    const float* __restrict__ zx,
    float* __restrict__ out)
{
  __shared__ float a_lds[RPB][512];      // [r][0..255]=x (non-PRE), [r][256..511]=h
  __shared__ float z_lds[RPB][1024];     // A: z[j]; B/E: 4x k-split partials
  __shared__ float z2_lds[RPB][1024];    // C: 4 G-quarter partials
  __shared__ float qf_lds[RPB][256];     // combined q + bias
  __shared__ float u_lds[RPB][52];
  __shared__ unsigned char mask_lds[RPB][64];
  __shared__ float ms_lds[RPB][4][2];
  __shared__ int   idx_lds[RPB];
  __shared__ float red_lds[16];
  __shared__ float eta_lds[RPB];

  const int tid  = threadIdx.x;
  const int col  = tid & 255;
  const int rr   = tid >> 8;             // row owned in gates/B2/E2/G2 (0..3)
  const int wav  = tid >> 6;             // 0..15
  const int lane = tid & 63;
  const int b0   = blockIdx.x * RPB;
  const int cr   = wav >> 2;             // C/F row (4 waves per row)
  const int cq   = wav & 3;              // n-quarter
  const int n0   = cq * 13;
  const int n1   = (cq == 3) ? NSTEP : (n0 + 13);
  const int kq   = rr;                   // B/E k-split quarter (64 k each)

  float c_reg, ln_reg;

  // ---- init state ----
  {
    const int b = b0 + rr;
    a_lds[rr][256 + col] = hidden_h[(size_t)b * HD + col];
    if (!PRE) a_lds[rr][col] = decoder_input[(size_t)b * HD + col];
    c_reg = hidden_c[(size_t)b * HD + col];
    float fn = 0.f;
#pragma unroll
    for (int k = 0; k < 5; ++k) fn += start_fea[b * 5 + k] * fn_w[col * 5 + k];
    ln_reg = fn;
  }
  if (tid < RPB * NSTEP) {
    const int r = tid / NSTEP, n = tid - r * NSTEP;
    mask_lds[r][n] = vmask[(size_t)(b0 + r) * NSTEP + n];
  }
  if (tid < RPB) { eta_lds[tid] = 0.f; idx_lds[tid] = NSTEP; }
  __syncthreads();
  if (tid < RPB) {
    bool all = true;
    for (int n = 0; n < NSTEP; ++n) all = all && (mask_lds[tid][n] != 0);
    if (all) mask_lds[tid][NSTEP - 1] = 0;
  }
  __syncthreads();

  const float bch0 = bc[col], bch1 = bc[col + 256], bch2 = bc[col + 512], bch3 = bc[col + 768];
  const float lw0 = eta_lw[col], lw1 = eta_lw[HD + col];
  const float etaB = eta_lb[0];
  const float bqg = glp_bq[col], bqp = ptr_bq[col];
  const float4 v4g = *(const float4*)&glp_v[lane << 2];
  const float4 v4p = *(const float4*)&ptr_v[lane << 2];

  for (int t = 0; t < NSTEP; ++t) {
    // ---- A: one z-col per thread (j=tid) for all 4 rows; W read once/block ----
    {
      float acc[RPB];
      if (PRE) {
#pragma unroll
        for (int i = 0; i < RPB; ++i)
          acc[i] = zx[((size_t)idx_lds[i] * BSZ + (b0 + i)) * 1024 + tid];
        const float* wp = wT2 + (size_t)256 * 1024 + tid;
        for (int k = 0; k < 256; k += 4) {
          const float w0 = wp[(size_t)(k + 0) * 1024];
          const float w1 = wp[(size_t)(k + 1) * 1024];
          const float w2 = wp[(size_t)(k + 2) * 1024];
          const float w3 = wp[(size_t)(k + 3) * 1024];
#pragma unroll
          for (int i = 0; i < RPB; ++i) {
            const float4 a4 = *(const float4*)&a_lds[i][256 + k];   // wave-uniform -> LDS broadcast
            acc[i] += a4.x * w0 + a4.y * w1 + a4.z * w2 + a4.w * w3;
          }
        }
      } else {
#pragma unroll
        for (int i = 0; i < RPB; ++i) acc[i] = 0.f;
        const float* wp = wT2 + tid;
        for (int k = 0; k < 512; k += 4) {
          const float w0 = wp[(size_t)(k + 0) * 1024];
          const float w1 = wp[(size_t)(k + 1) * 1024];
          const float w2 = wp[(size_t)(k + 2) * 1024];
          const float w3 = wp[(size_t)(k + 3) * 1024];
#pragma unroll
          for (int i = 0; i < RPB; ++i) {
            const float4 a4 = *(const float4*)&a_lds[i][k];
            acc[i] += a4.x * w0 + a4.y * w1 + a4.z * w2 + a4.w * w3;
          }
        }
      }
#pragma unroll
      for (int i = 0; i < RPB; ++i) z_lds[i][tid] = acc[i];
    }
    __syncthreads();
    // ---- gates: thread (rr,col) ----
    {
      const float4 z4 = *(const float4*)&z_lds[rr][col << 2];
      const float zi = z4.x + bch0, zf = z4.y + bch1, zg = z4.z + bch2, zo = z4.w + bch3;
      const float cn = sigf(zf) * c_reg + sigf(zi) * tanh_fast(zg);
      c_reg = cn;
      a_lds[rr][256 + col] = sigf(zo) * tanh_fast(cn);
    }
    __syncthreads();
    // ---- B: q_glp partials, 4-way k-split (kq=rr) ----
    {
      float accB[RPB] = {0.f, 0.f, 0.f, 0.f};
      const int kb = kq << 6;
      for (int k = kb; k < kb + 64; k += 4) {
        const float w0 = wqTg[(size_t)(k + 0) * 256 + col];
        const float w1 = wqTg[(size_t)(k + 1) * 256 + col];
        const float w2 = wqTg[(size_t)(k + 2) * 256 + col];
        const float w3 = wqTg[(size_t)(k + 3) * 256 + col];
#pragma unroll
        for (int i = 0; i < RPB; ++i) {
          const float4 a4 = *(const float4*)&a_lds[i][256 + k];     // wave-uniform
          accB[i] += a4.x * w0 + a4.y * w1 + a4.z * w2 + a4.w * w3;
        }
      }
#pragma unroll
      for (int i = 0; i < RPB; ++i) z_lds[i][(kq << 8) + col] = accB[i];
    }
    __syncthreads();
    // ---- B2: qf = sum of 4 partials + bias ----
    qf_lds[rr][col] = z_lds[rr][col] + z_lds[rr][256 + col]
                    + z_lds[rr][512 + col] + z_lds[rr][768 + col] + bqg;
    __syncthreads();
    // ---- C: fused glimpse, 4 waves/row, online softmax, e_glp read once ----
    {
      const int r = cr, b = b0 + r;
      const float4 q4 = *(const float4*)&qf_lds[r][lane << 2];
      float m = NEG_INF, s = 0.f;
      float4 G = make_float4(0.f, 0.f, 0.f, 0.f);
      const float* eb = e_glp + (size_t)b * NSTEP * HD;
      for (int n = n0; n < n1; ++n) {
        if (mask_lds[r][n]) continue;
        const float4 e4 = *(const float4*)&eb[n * HD + (lane << 2)];
        float uu = v4g.x * tanh_fast(q4.x + e4.x) + v4g.y * tanh_fast(q4.y + e4.y)
                 + v4g.z * tanh_fast(q4.z + e4.z) + v4g.w * tanh_fast(q4.w + e4.w);
        uu = wave_sum(uu);
        if (uu > m) {
          const float sc = __expf(m - uu);
          s *= sc; G.x *= sc; G.y *= sc; G.z *= sc; G.w *= sc;
          m = uu;
        }
        const float p = __expf(uu - m);
        s += p;
        G.x += p * e4.x; G.y += p * e4.y; G.z += p * e4.z; G.w += p * e4.w;
      }
      if (lane == 0) { ms_lds[r][cq][0] = m; ms_lds[r][cq][1] = s; }
      __syncthreads();
      float mg = NEG_INF;
#pragma unroll
      for (int q = 0; q < 4; ++q) mg = fmaxf(mg, ms_lds[r][q][0]);
      float Z = 0.f;
#pragma unroll
      for (int q = 0; q < 4; ++q) Z += ms_lds[r][q][1] * __expf(ms_lds[r][q][0] - mg);
      const float sc = __expf(m - mg) / Z;
      G.x *= sc; G.y *= sc; G.z *= sc; G.w *= sc;
      *(float4*)&z2_lds[r][(cq << 8) + (lane << 2)] = G;
    }
    __syncthreads();
    // ---- E: q_ptr partials from g_l = sum of 4 G-quarters, k-split ----
    {
      float accE[RPB] = {0.f, 0.f, 0.f, 0.f};
      const int kb = kq << 6;
      for (int k = kb; k < kb + 64; k += 4) {
        const float w0 = wqTp[(size_t)(k + 0) * 256 + col];
        const float w1 = wqTp[(size_t)(k + 1) * 256 + col];
        const float w2 = wqTp[(size_t)(k + 2) * 256 + col];
        const float w3 = wqTp[(size_t)(k + 3) * 256 + col];
#pragma unroll
        for (int i = 0; i < RPB; ++i) {
          const float4 g0 = *(const float4*)&z2_lds[i][k];          // wave-uniform
          const float4 g1 = *(const float4*)&z2_lds[i][256 + k];
          const float4 g2 = *(const float4*)&z2_lds[i][512 + k];
          const float4 g3 = *(const float4*)&z2_lds[i][768 + k];
          const float gx = g0.x + g1.x + g2.x + g3.x;
          const float gy = g0.y + g1.y + g2.y + g3.y;
          const float gz = g0.z + g1.z + g2.z + g3.z;
          const float gw = g0.w + g1.w + g2.w + g3.w;
          accE[i] += gx * w0 + gy * w1 + gz * w2 + gw * w3;
        }
      }
#pragma unroll
      for (int i = 0; i < RPB; ++i) z_lds[i][(kq << 8) + col] = accE[i];
    }
    __syncthreads();
    // ---- E2 ----
    qf_lds[rr][col] = z_lds[rr][col] + z_lds[rr][256 + col]
                    + z_lds[rr][512 + col] + z_lds[rr][768 + col] + bqp;
    __syncthreads();
    // ---- F: u_ptr, 4 waves/row, mask-skip ----
    {
      const int r = cr, b = b0 + r;
      const float4 q4 = *(const float4*)&qf_lds[r][lane << 2];
      const float* eb = e_ptr + (size_t)b * NSTEP * HD;
      for (int n = n0; n < n1; ++n) {
        if (mask_lds[r][n]) continue;
        const float4 e4 = *(const float4*)&eb[n * HD + (lane << 2)];
        float uu = v4p.x * tanh_fast(q4.x + e4.x) + v4p.y * tanh_fast(q4.y + e4.y)
                 + v4p.z * tanh_fast(q4.z + e4.z) + v4p.w * tanh_fast(q4.w + e4.w);
        uu = wave_sum(uu);
        if (lane == 0) u_lds[r][n] = uu;
      }
    }
    __syncthreads();
    // ---- F2: logits, log_softmax (finite clamp), argmax (waves 0..3) ----
    if (wav < RPB) {
      const int r = wav, b = b0 + r;
      const bool mk = (lane < NSTEP) ? (mask_lds[r][lane] != 0) : true;
      const float lg = mk ? NEG_INF : (10.f * tanh_fast(u_lds[r][lane]));
      const float m  = wave_max(lg);
      const float ex = mk ? 0.f : __expf(lg - m);
      const float ss = wave_sum(ex);
      const float ls = __logf(ss);
      if (lane < NSTEP)
        out[(size_t)b * (NSTEP * NSTEP) + (size_t)t * NSTEP + lane] =
            mk ? -1.0e30f : ((lg - m) - ls);
      float av = lg;
      int   ai = lane;
#pragma unroll
      for (int o = 1; o < 64; o <<= 1) {
        const float ov = __shfl_xor(av, o);
        const int   oi = __shfl_xor(ai, o);
        if (ov > av || (ov == av && oi < ai)) { av = ov; ai = oi; }
      }
      if (lane == 0) {
        idx_lds[r] = ai;
        out[OFF_SEL + (size_t)b * NSTEP + t] = (float)ai;
      }
    }
    __syncthreads();
    // ---- G2: gathers + eta (thread owns (rr,col)) ----
    {
      const int b = b0 + rr;
      const int ix = idx_lds[rr];
      const float cur = context[((size_t)ix * BSZ + b) * HD + col];
      float pr = ln_reg * lw0 + cur * lw1;
      ln_reg = cur;
      if (!PRE) a_lds[rr][col] = embedded[((size_t)ix * BSZ + b) * HD + col];
      pr = wave_sum(pr);
      if (lane == 0) red_lds[wav] = pr;
    }
    __syncthreads();
    if (tid < RPB) {
      const int r = tid;
      const float s = red_lds[r * 4 + 0] + red_lds[r * 4 + 1]
                    + red_lds[r * 4 + 2] + red_lds[r * 4 + 3];
      const float ev = eta_lds[r] + s + etaB;
      eta_lds[r] = ev;
      out[OFF_ETA + (size_t)(b0 + r) * NSTEP + t] = ev;
      const int ix = idx_lds[r];
      mask_lds[r][ix] = 1;
      bool all = true;
      for (int n = 0; n < NSTEP; ++n) all = all && (mask_lds[r][n] != 0);
      if (all) mask_lds[r][NSTEP - 1] = 0;
    }
    __syncthreads();
  }
}

extern "C" void kernel_launch(void* const* d_in, const int* in_sizes, int n_in,
                              void* d_out, int out_size, void* d_ws, size_t ws_size,
                              hipStream_t stream) {
  const float* start_fea  = (const float*)d_in[0];
  const float* decoder_in = (const float*)d_in[1];
  const float* embedded   = (const float*)d_in[2];
  const float* hidden_h   = (const float*)d_in[3];
  const float* hidden_c   = (const float*)d_in[4];
  const float* context    = (const float*)d_in[5];
  // d_in[6] = V: unused by outputs
  const unsigned char* vmask = (const unsigned char*)d_in[7];
  const float* lstm_w_ih  = (const float*)d_in[8];
  const float* lstm_w_hh  = (const float*)d_in[9];
  const float* lstm_b_ih  = (const float*)d_in[10];
  const float* lstm_b_hh  = (const float*)d_in[11];
  const float* ptr_wq     = (const float*)d_in[12];
  const float* ptr_bq     = (const float*)d_in[13];
  const float* ptr_wr     = (const float*)d_in[14];
  const float* ptr_br     = (const float*)d_in[15];
  const float* ptr_v      = (const float*)d_in[16];
  const float* glp_wq     = (const float*)d_in[17];
  const float* glp_bq     = (const float*)d_in[18];
  const float* glp_wr     = (const float*)d_in[19];
  const float* glp_br     = (const float*)d_in[20];
  const float* glp_v      = (const float*)d_in[21];
  const float* fn_w       = (const float*)d_in[22];
  // d_in[23..26] = eta LSTM: dead code (outputs never read heh/cec)
  const float* eta_lw     = (const float*)d_in[27];
  const float* eta_lb     = (const float*)d_in[28];

  float* ws    = (float*)d_ws;
  float* e_glp = ws;                                       // 13,107,200 f32
  float* e_ptr = e_glp + (size_t)BSZ * NSTEP * HD;         // 13,107,200 f32
  float* wT2   = e_ptr + (size_t)BSZ * NSTEP * HD;         // 524,288 f32
  float* bc    = wT2 + (size_t)512 * 1024;                 // 1,024
  float* wqTg  = bc + 1024;                                // 65,536
  float* wqTp  = wqTg + 65536;                             // 65,536
  float* zx    = wqTp + 65536;                             // 53,477,376 f32 (optional)

  const size_t need_pre =
      ((size_t)BSZ * NSTEP * HD * 2 + (size_t)512 * 1024 + 1024 + 2 * 65536 +
       (size_t)(NSTEP + 1) * BSZ * 1024) * sizeof(float);
  const bool pre = (ws_size >= need_pre);

  init_kernel<<<772, 256, 0, stream>>>(lstm_w_ih, lstm_w_hh, lstm_b_ih, lstm_b_hh,
                                       glp_wq, ptr_wq, wT2, bc, wqTg, wqTp);
  e_kernel<<<NSTEP * 32, 256, 0, stream>>>(context, glp_wr, glp_br, ptr_wr, ptr_br, e_glp, e_ptr);
  if (pre) {
    zx_kernel<<<(NSTEP + 1) * 32, 256, 0, stream>>>(embedded, decoder_in, wT2, zx);
    dec_kernel<1><<<BSZ / RPB, 1024, 0, stream>>>(
        start_fea, decoder_in, embedded, hidden_h, hidden_c, context, vmask,
        glp_bq, glp_v, ptr_bq, ptr_v, fn_w, eta_lw, eta_lb,
        wT2, bc, wqTg, wqTp, e_glp, e_ptr, zx, (float*)d_out);
  } else {
    dec_kernel<0><<<BSZ / RPB, 1024, 0, stream>>>(
        start_fea, decoder_in, embedded, hidden_h, hidden_c, context, vmask,
        glp_bq, glp_v, ptr_bq, ptr_v, fn_w, eta_lw, eta_lb,
        wT2, bc, wqTg, wqTp, e_glp, e_ptr, zx, (float*)d_out);
  }
}